// Round 1
// baseline (1602.714 us; speedup 1.0000x reference)
//
#include <hip/hip_runtime.h>

// 3-layer GCN: per layer  support = act(h) @ W ;  agg = b + scatter_add(w_e * support[col], row)
// N=100000, E=1000000, dims 64 -> 64 -> 32 -> 16, leaky_relu slope 0.25.

__device__ __forceinline__ float lrelu(float v) { return v > 0.0f ? v : 0.25f * v; }

// out[n*M + m] = sum_k act(in[n*K + k]) * W[k*M + m]
template <int K, int M, bool ACT>
__global__ void gemm_kernel(const float* __restrict__ in, const float* __restrict__ W,
                            float* __restrict__ out, int N) {
    __shared__ float Ws[K * M];
    for (int i = threadIdx.x; i < K * M; i += blockDim.x) Ws[i] = W[i];
    __syncthreads();
    int tid = blockIdx.x * blockDim.x + threadIdx.x;
    int total = N * M;
    if (tid >= total) return;
    int n = tid / M;
    int m = tid - n * M;
    const float* __restrict__ xr = in + (long)n * K;
    float acc = 0.0f;
#pragma unroll
    for (int k = 0; k < K; ++k) {
        float v = xr[k];                 // same addr across the node's lanes -> L1 broadcast
        if (ACT) v = lrelu(v);
        acc += v * Ws[k * M + m];        // consecutive m -> 2-way LDS alias (free)
    }
    out[tid] = acc;
}

// agg[n*M + m] = b[m]   (float4-vectorized)
template <int M>
__global__ void init_bias_kernel(const float* __restrict__ b, float* __restrict__ agg, int N) {
    const int QM = M / 4;
    int tid = blockIdx.x * blockDim.x + threadIdx.x;
    int total = N * QM;
    if (tid >= total) return;
    int q = tid - (tid / QM) * QM;
    reinterpret_cast<float4*>(agg)[tid] = reinterpret_cast<const float4*>(b)[q];
}

// For each edge e, each q in [0, M/4): agg[row[e]][4q..4q+3] += w[e] * support[col[e]][4q..4q+3]
template <int M>
__global__ void scatter_kernel(const int* __restrict__ row, const int* __restrict__ col,
                               const float* __restrict__ ew, const float* __restrict__ sup,
                               float* __restrict__ agg, int E) {
    const int QM = M / 4;
    int tid = blockIdx.x * blockDim.x + threadIdx.x;
    if (tid >= E * QM) return;
    int e = tid / QM;
    int q = tid - e * QM;
    int r = row[e];
    int c = col[e];
    float w = ew[e];
    float4 v = *reinterpret_cast<const float4*>(sup + (long)c * M + q * 4);  // 256B/edge contiguous
    float* dst = agg + (long)r * M + q * 4;
    atomicAdd(dst + 0, w * v.x);
    atomicAdd(dst + 1, w * v.y);
    atomicAdd(dst + 2, w * v.z);
    atomicAdd(dst + 3, w * v.w);
}

// in-place leaky relu on the final output
__global__ void lrelu_kernel(float* __restrict__ p, int total4) {
    int tid = blockIdx.x * blockDim.x + threadIdx.x;
    if (tid >= total4) return;
    float4 v = reinterpret_cast<float4*>(p)[tid];
    v.x = lrelu(v.x); v.y = lrelu(v.y); v.z = lrelu(v.z); v.w = lrelu(v.w);
    reinterpret_cast<float4*>(p)[tid] = v;
}

extern "C" void kernel_launch(void* const* d_in, const int* in_sizes, int n_in,
                              void* d_out, int out_size, void* d_ws, size_t ws_size,
                              hipStream_t stream) {
    const float* x    = (const float*)d_in[0];
    const int*   erow = (const int*)  d_in[1];
    const int*   ecol = (const int*)  d_in[2];
    const float* ew   = (const float*)d_in[3];
    const float* W1   = (const float*)d_in[4];
    const float* b1   = (const float*)d_in[5];
    const float* W2   = (const float*)d_in[6];
    const float* b2   = (const float*)d_in[7];
    const float* W3   = (const float*)d_in[8];
    const float* b3   = (const float*)d_in[9];
    float* out = (float*)d_out;

    const int N = in_sizes[0] / 64;   // 100000
    const int E = in_sizes[1];        // 1000000

    // Workspace layout (bytes). Peak 51.2 MB with reuse:
    //   s1  : [0,               N*64*4)           25.6 MB
    //   agg1: [N*64*4,          2*N*64*4)         25.6 MB
    //   s2  : reuse s1 region                     12.8 MB
    //   agg2: [N*32*4,          N*64*4)           12.8 MB  (2nd half of s1 region)
    //   s3  : reuse agg1 region                    6.4 MB
    char* wsc = (char*)d_ws;
    const size_t SZ64 = (size_t)N * 64 * sizeof(float);
    const size_t SZ32 = (size_t)N * 32 * sizeof(float);
    float* s1   = (float*)(wsc);
    float* agg1 = (float*)(wsc + SZ64);
    float* s2   = (float*)(wsc);
    float* agg2 = (float*)(wsc + SZ32);
    float* s3   = (float*)(wsc + SZ64);

    const int B = 256;
    auto cdiv = [](long a, long b) { return (int)((a + b - 1) / b); };

    // Layer 1: d_in=64 -> d1=64
    gemm_kernel<64, 64, false><<<cdiv((long)N * 64, B), B, 0, stream>>>(x, W1, s1, N);
    init_bias_kernel<64><<<cdiv((long)N * 16, B), B, 0, stream>>>(b1, agg1, N);
    scatter_kernel<64><<<cdiv((long)E * 16, B), B, 0, stream>>>(erow, ecol, ew, s1, agg1, E);

    // Layer 2: 64 -> 32 (lrelu applied to agg1 on load)
    gemm_kernel<64, 32, true><<<cdiv((long)N * 32, B), B, 0, stream>>>(agg1, W2, s2, N);
    init_bias_kernel<32><<<cdiv((long)N * 8, B), B, 0, stream>>>(b2, agg2, N);
    scatter_kernel<32><<<cdiv((long)E * 8, B), B, 0, stream>>>(erow, ecol, ew, s2, agg2, E);

    // Layer 3: 32 -> 16 (lrelu applied to agg2 on load); aggregate straight into d_out
    gemm_kernel<32, 16, true><<<cdiv((long)N * 16, B), B, 0, stream>>>(agg2, W3, s3, N);
    init_bias_kernel<16><<<cdiv((long)N * 4, B), B, 0, stream>>>(b3, out, N);
    scatter_kernel<16><<<cdiv((long)E * 4, B), B, 0, stream>>>(erow, ecol, ew, s3, out, E);

    // Final activation in place on d_out
    lrelu_kernel<<<cdiv((long)N * 16 / 4, B), B, 0, stream>>>(out, N * 16 / 4);
}

// Round 2
// 370.422 us; speedup vs baseline: 4.3267x; 4.3267x over previous
//
#include <hip/hip_runtime.h>

// 3-layer GCN, N=100000 nodes, E=1000000 edges, dims 64 -> 64 -> 32 -> 16.
// Per layer: support = act(h) @ W ; out = b + segment_sum(w_e * support[col], row).
// Strategy: build CSR (edges grouped by destination row) once per launch, then
// aggregate gather-style with zero float atomics.

__device__ __forceinline__ float lrelu(float v) { return v > 0.0f ? v : 0.25f * v; }

// ---------------- CSR build ----------------

constexpr int SCAN_T = 256;
constexpr int SCAN_PER = 8;
constexpr int SCAN_CHUNK = SCAN_T * SCAN_PER;  // 2048

__global__ void hist_kernel(const int* __restrict__ row, int* __restrict__ cnt, int E) {
    int e = blockIdx.x * blockDim.x + threadIdx.x;
    if (e < E) atomicAdd(&cnt[row[e]], 1);
}

// Per-chunk inclusive scan of cnt into rs; chunk totals to bsum.
__global__ void scan1_kernel(const int* __restrict__ cnt, int* __restrict__ rs,
                             int* __restrict__ bsum, int N) {
    __shared__ int lds[SCAN_T];
    int t = threadIdx.x;
    int base = blockIdx.x * SCAN_CHUNK + t * SCAN_PER;
    int v[SCAN_PER];
    int run = 0;
#pragma unroll
    for (int j = 0; j < SCAN_PER; ++j) {
        int i = base + j;
        run += (i < N) ? cnt[i] : 0;
        v[j] = run;
    }
    lds[t] = run;
    __syncthreads();
    for (int off = 1; off < SCAN_T; off <<= 1) {
        int add = (t >= off) ? lds[t - off] : 0;
        __syncthreads();
        lds[t] += add;
        __syncthreads();
    }
    int excl = lds[t] - run;
#pragma unroll
    for (int j = 0; j < SCAN_PER; ++j) {
        int i = base + j;
        if (i < N) rs[i] = v[j] + excl;
    }
    if (t == SCAN_T - 1) bsum[blockIdx.x] = lds[t];
}

// Exclusive scan of chunk totals (nb ~ 49: single-thread is fine).
__global__ void scan2_kernel(const int* __restrict__ bsum, int* __restrict__ bofs, int nb) {
    if (threadIdx.x == 0 && blockIdx.x == 0) {
        int run = 0;
        for (int i = 0; i < nb; ++i) { bofs[i] = run; run += bsum[i]; }
    }
}

// Add chunk offsets -> rs becomes global inclusive scan (segment ends);
// cursor[i] = segment start = end - count.
__global__ void scan3_kernel(const int* __restrict__ cnt, int* __restrict__ rs,
                             int* __restrict__ cursor, const int* __restrict__ bofs, int N) {
    int i = blockIdx.x * blockDim.x + threadIdx.x;
    if (i >= N) return;
    int e = rs[i] + bofs[i / SCAN_CHUNK];
    rs[i] = e;
    cursor[i] = e - cnt[i];
}

__global__ void scatter_edges_kernel(const int* __restrict__ row, const int* __restrict__ col,
                                     const float* __restrict__ w, int* __restrict__ cursor,
                                     int* __restrict__ scol, float* __restrict__ sw, int E) {
    int e = blockIdx.x * blockDim.x + threadIdx.x;
    if (e >= E) return;
    int r = row[e];
    int pos = atomicAdd(&cursor[r], 1);   // int atomic, low contention (avg deg 10)
    scol[pos] = col[e];
    sw[pos] = w[e];
}

// ---------------- dense transform ----------------

// out[n][m] = sum_k act(in[n][k]) * W[k][m], one float4 of outputs per thread.
template <int K, int M, bool ACT>
__global__ void gemm_kernel(const float* __restrict__ in, const float* __restrict__ W,
                            float* __restrict__ out, int N) {
    __shared__ float Ws[K * M];
    for (int i = threadIdx.x; i < K * M; i += blockDim.x) Ws[i] = W[i];
    __syncthreads();
    const int QM = M / 4;
    int tid = blockIdx.x * blockDim.x + threadIdx.x;
    if (tid >= N * QM) return;
    int n = tid / QM;
    int q = tid - n * QM;
    const float* __restrict__ xr = in + (size_t)n * K;
    float4 acc = {0.f, 0.f, 0.f, 0.f};
#pragma unroll
    for (int k0 = 0; k0 < K; k0 += 4) {
        float4 xv = *reinterpret_cast<const float4*>(xr + k0);
        if (ACT) { xv.x = lrelu(xv.x); xv.y = lrelu(xv.y); xv.z = lrelu(xv.z); xv.w = lrelu(xv.w); }
        const float* wr = &Ws[k0 * M + q * 4];
        float4 w0 = *reinterpret_cast<const float4*>(wr);
        float4 w1 = *reinterpret_cast<const float4*>(wr + M);
        float4 w2 = *reinterpret_cast<const float4*>(wr + 2 * M);
        float4 w3 = *reinterpret_cast<const float4*>(wr + 3 * M);
        acc.x += xv.x * w0.x + xv.y * w1.x + xv.z * w2.x + xv.w * w3.x;
        acc.y += xv.x * w0.y + xv.y * w1.y + xv.z * w2.y + xv.w * w3.y;
        acc.z += xv.x * w0.z + xv.y * w1.z + xv.z * w2.z + xv.w * w3.z;
        acc.w += xv.x * w0.w + xv.y * w1.w + xv.z * w2.w + xv.w * w3.w;
    }
    *reinterpret_cast<float4*>(out + (size_t)n * M + q * 4) = acc;
}

// ---------------- CSR aggregation (no atomics) ----------------

// M lanes per node; lane m accumulates out[node][m] = b[m] + sum_j sw[j]*sup[scol[j]][m].
template <int M, bool ACTOUT>
__global__ void agg_kernel(const int* __restrict__ rs, const int* __restrict__ scol,
                           const float* __restrict__ sw, const float* __restrict__ sup,
                           const float* __restrict__ b, float* __restrict__ out, int N) {
    int tid = blockIdx.x * blockDim.x + threadIdx.x;
    int node = tid / M;
    if (node >= N) return;
    int m = tid - node * M;
    int beg = node ? rs[node - 1] : 0;
    int end = rs[node];
    float acc = 0.0f;
    for (int j = beg; j < end; ++j) {
        acc += sw[j] * sup[(size_t)scol[j] * M + m];  // row read coalesced across the M lanes
    }
    acc += b[m];
    if (ACTOUT) acc = lrelu(acc);
    out[(size_t)node * M + m] = acc;
}

extern "C" void kernel_launch(void* const* d_in, const int* in_sizes, int n_in,
                              void* d_out, int out_size, void* d_ws, size_t ws_size,
                              hipStream_t stream) {
    const float* x    = (const float*)d_in[0];
    const int*   erow = (const int*)  d_in[1];
    const int*   ecol = (const int*)  d_in[2];
    const float* ew   = (const float*)d_in[3];
    const float* W1   = (const float*)d_in[4];
    const float* b1   = (const float*)d_in[5];
    const float* W2   = (const float*)d_in[6];
    const float* b2   = (const float*)d_in[7];
    const float* W3   = (const float*)d_in[8];
    const float* b3   = (const float*)d_in[9];
    float* out = (float*)d_out;

    const int N = in_sizes[0] / 64;   // 100000
    const int E = in_sizes[1];        // 1000000

    // Workspace layout:
    //   [0, SZ64)        s1 (25.6MB); later s2 in first half, a2 in second half
    //   [SZ64, 2*SZ64)   a1 (25.6MB); later s3
    //   [2*SZ64, ...)    CSR: cnt[N], rs[N], cursor[N], bsum[64], bofs[64], scol[E], sw[E]
    char* wsc = (char*)d_ws;
    const size_t SZ64 = (size_t)N * 64 * sizeof(float);
    const size_t SZ32 = (size_t)N * 32 * sizeof(float);
    float* s1 = (float*)(wsc);
    float* a1 = (float*)(wsc + SZ64);
    float* s2 = (float*)(wsc);
    float* a2 = (float*)(wsc + SZ32);
    float* s3 = (float*)(wsc + SZ64);

    char* csr = wsc + 2 * SZ64;
    int*   cnt    = (int*)csr;
    int*   rs     = (int*)(csr + (size_t)N * 4);
    int*   cursor = (int*)(csr + (size_t)N * 8);
    int*   bsum   = (int*)(csr + (size_t)N * 12);
    int*   bofs   = bsum + 64;
    int*   scol   = bofs + 64;
    float* sw     = (float*)(scol + E);

    const int B = 256;
    auto cdiv = [](long a, long b) { return (int)((a + b - 1) / b); };
    const int nb = cdiv(N, SCAN_CHUNK);

    // ---- CSR build (once; shared by all 3 layers) ----
    hipMemsetAsync(cnt, 0, (size_t)N * sizeof(int), stream);
    hist_kernel<<<cdiv(E, B), B, 0, stream>>>(erow, cnt, E);
    scan1_kernel<<<nb, SCAN_T, 0, stream>>>(cnt, rs, bsum, N);
    scan2_kernel<<<1, 64, 0, stream>>>(bsum, bofs, nb);
    scan3_kernel<<<cdiv(N, B), B, 0, stream>>>(cnt, rs, cursor, bofs, N);
    scatter_edges_kernel<<<cdiv(E, B), B, 0, stream>>>(erow, ecol, ew, cursor, scol, sw, E);

    // ---- Layer 1: 64 -> 64 ----
    gemm_kernel<64, 64, false><<<cdiv((long)N * 16, B), B, 0, stream>>>(x, W1, s1, N);
    agg_kernel<64, false><<<cdiv((long)N * 64, B), B, 0, stream>>>(rs, scol, sw, s1, b1, a1, N);

    // ---- Layer 2: 64 -> 32 (lrelu on load) ----
    gemm_kernel<64, 32, true><<<cdiv((long)N * 8, B), B, 0, stream>>>(a1, W2, s2, N);
    agg_kernel<32, false><<<cdiv((long)N * 32, B), B, 0, stream>>>(rs, scol, sw, s2, b2, a2, N);

    // ---- Layer 3: 32 -> 16 (lrelu on load; lrelu fused into output write) ----
    gemm_kernel<32, 16, true><<<cdiv((long)N * 4, B), B, 0, stream>>>(a2, W3, s3, N);
    agg_kernel<16, true><<<cdiv((long)N * 16, B), B, 0, stream>>>(rs, scol, sw, s3, b3, out, N);
}

// Round 3
// 304.427 us; speedup vs baseline: 5.2647x; 1.2168x over previous
//
#include <hip/hip_runtime.h>
#include <hip/hip_bf16.h>

// 3-layer GCN, N=100000, E=1000000, dims 64 -> 64 -> 32 -> 16.
// support = act(h) @ W  (bf16 out); agg = b + segment_sum(w_e * sup[col], row) via CSR.
// Edge records packed as int2{col, w_bits}; per-segment cooperative load + shfl broadcast.

__device__ __forceinline__ float lrelu(float v) { return v > 0.0f ? v : 0.25f * v; }

// ---------------- CSR build ----------------

constexpr int SCAN_T = 256;
constexpr int SCAN_PER = 8;
constexpr int SCAN_CHUNK = SCAN_T * SCAN_PER;  // 2048

__global__ void hist_kernel(const int* __restrict__ row, int* __restrict__ cnt, int E) {
    int e = blockIdx.x * blockDim.x + threadIdx.x;
    if (e < E) atomicAdd(&cnt[row[e]], 1);
}

__global__ void scan1_kernel(const int* __restrict__ cnt, int* __restrict__ rs,
                             int* __restrict__ bsum, int N) {
    __shared__ int lds[SCAN_T];
    int t = threadIdx.x;
    int base = blockIdx.x * SCAN_CHUNK + t * SCAN_PER;
    int v[SCAN_PER];
    int run = 0;
#pragma unroll
    for (int j = 0; j < SCAN_PER; ++j) {
        int i = base + j;
        run += (i < N) ? cnt[i] : 0;
        v[j] = run;
    }
    lds[t] = run;
    __syncthreads();
    for (int off = 1; off < SCAN_T; off <<= 1) {
        int add = (t >= off) ? lds[t - off] : 0;
        __syncthreads();
        lds[t] += add;
        __syncthreads();
    }
    int excl = lds[t] - run;
#pragma unroll
    for (int j = 0; j < SCAN_PER; ++j) {
        int i = base + j;
        if (i < N) rs[i] = v[j] + excl;
    }
    if (t == SCAN_T - 1) bsum[blockIdx.x] = lds[t];
}

__global__ void scan2_kernel(const int* __restrict__ bsum, int* __restrict__ bofs, int nb) {
    if (threadIdx.x == 0 && blockIdx.x == 0) {
        int run = 0;
        for (int i = 0; i < nb; ++i) { bofs[i] = run; run += bsum[i]; }
    }
}

__global__ void scan3_kernel(const int* __restrict__ cnt, int* __restrict__ rs,
                             int* __restrict__ cursor, const int* __restrict__ bofs, int N) {
    int i = blockIdx.x * blockDim.x + threadIdx.x;
    if (i >= N) return;
    int e = rs[i] + bofs[i / SCAN_CHUNK];
    rs[i] = e;
    cursor[i] = e - cnt[i];
}

__global__ void scatter_edges_kernel(const int* __restrict__ row, const int* __restrict__ col,
                                     const float* __restrict__ w, int* __restrict__ cursor,
                                     int2* __restrict__ edges, int E) {
    int e = blockIdx.x * blockDim.x + threadIdx.x;
    if (e >= E) return;
    int r = row[e];
    int pos = atomicAdd(&cursor[r], 1);           // int atomic, avg 10 contenders
    edges[pos] = make_int2(col[e], __float_as_int(w[e]));  // single 8B store
}

// ---------------- dense transform (f32 in, bf16 out) ----------------

template <int K, int M, bool ACT>
__global__ void gemm_kernel(const float* __restrict__ in, const float* __restrict__ W,
                            __hip_bfloat16* __restrict__ out, int N) {
    __shared__ float Ws[K * M];
    for (int i = threadIdx.x; i < K * M; i += blockDim.x) Ws[i] = W[i];
    __syncthreads();
    const int QM = M / 4;
    int tid = blockIdx.x * blockDim.x + threadIdx.x;
    if (tid >= N * QM) return;
    int n = tid / QM;
    int q = tid - n * QM;
    const float* __restrict__ xr = in + (size_t)n * K;
    float4 acc = {0.f, 0.f, 0.f, 0.f};
#pragma unroll
    for (int k0 = 0; k0 < K; k0 += 4) {
        float4 xv = *reinterpret_cast<const float4*>(xr + k0);
        if (ACT) { xv.x = lrelu(xv.x); xv.y = lrelu(xv.y); xv.z = lrelu(xv.z); xv.w = lrelu(xv.w); }
        const float* wr = &Ws[k0 * M + q * 4];
        float4 w0 = *reinterpret_cast<const float4*>(wr);
        float4 w1 = *reinterpret_cast<const float4*>(wr + M);
        float4 w2 = *reinterpret_cast<const float4*>(wr + 2 * M);
        float4 w3 = *reinterpret_cast<const float4*>(wr + 3 * M);
        acc.x += xv.x * w0.x + xv.y * w1.x + xv.z * w2.x + xv.w * w3.x;
        acc.y += xv.x * w0.y + xv.y * w1.y + xv.z * w2.y + xv.w * w3.y;
        acc.z += xv.x * w0.z + xv.y * w1.z + xv.z * w2.z + xv.w * w3.z;
        acc.w += xv.x * w0.w + xv.y * w1.w + xv.z * w2.w + xv.w * w3.w;
    }
    alignas(8) __hip_bfloat16 o[4] = {
        __float2bfloat16(acc.x), __float2bfloat16(acc.y),
        __float2bfloat16(acc.z), __float2bfloat16(acc.w)};
    *reinterpret_cast<uint2*>(out + (size_t)n * M + q * 4) = *reinterpret_cast<const uint2*>(o);
}

// ---------------- CSR aggregation (no atomics, cooperative edge load) ----------------

// M lanes per node. Segment edges loaded cooperatively (coalesced int2), broadcast
// via shfl; sup row gathers are independent -> MLP.
template <int M, bool ACTOUT>
__global__ void agg_kernel(const int* __restrict__ rs, const int2* __restrict__ edges,
                           const __hip_bfloat16* __restrict__ sup, const float* __restrict__ b,
                           float* __restrict__ out, int N, int E) {
    int tid = blockIdx.x * blockDim.x + threadIdx.x;
    int node = tid / M;
    if (node >= N) return;
    int m = tid - node * M;           // lane index within the M-lane group
    int beg = node ? rs[node - 1] : 0;
    int end = rs[node];
    float acc = 0.0f;
    for (int j0 = beg; j0 < end; j0 += M) {
        int jl = j0 + m;
        int2 ev = edges[jl < end ? jl : end - 1];   // coalesced; clamped lanes unused
        int cnt = min(M, end - j0);
#pragma unroll 4
        for (int jj = 0; jj < cnt; ++jj) {
            int   cb = __shfl(ev.x, jj, M);
            float wb = __int_as_float(__shfl(ev.y, jj, M));
            acc += wb * __bfloat162float(sup[(size_t)cb * M + m]);
        }
    }
    acc += b[m];
    if (ACTOUT) acc = lrelu(acc);
    out[(size_t)node * M + m] = acc;
}

extern "C" void kernel_launch(void* const* d_in, const int* in_sizes, int n_in,
                              void* d_out, int out_size, void* d_ws, size_t ws_size,
                              hipStream_t stream) {
    const float* x    = (const float*)d_in[0];
    const int*   erow = (const int*)  d_in[1];
    const int*   ecol = (const int*)  d_in[2];
    const float* ew   = (const float*)d_in[3];
    const float* W1   = (const float*)d_in[4];
    const float* b1   = (const float*)d_in[5];
    const float* W2   = (const float*)d_in[6];
    const float* b2   = (const float*)d_in[7];
    const float* W3   = (const float*)d_in[8];
    const float* b3   = (const float*)d_in[9];
    float* out = (float*)d_out;

    const int N = in_sizes[0] / 64;   // 100000
    const int E = in_sizes[1];        // 1000000

    // Workspace:
    //   region A [0, 25.6MB)      : a1 (f32 N*64); later a2 (f32 N*32)
    //   region B [25.6, 38.4MB)   : s1 (bf16 N*64); later s2 (bf16 N*32), s3 (bf16 N*16)
    //   CSR      [38.4MB, ...)    : cnt[N], rs[N], cursor[N], bsum[64], bofs[64], edges int2[E]
    char* wsc = (char*)d_ws;
    const size_t SZA = (size_t)N * 64 * sizeof(float);          // 25.6 MB
    const size_t SZB = (size_t)N * 64 * sizeof(__hip_bfloat16); // 12.8 MB
    float*          a1 = (float*)wsc;
    float*          a2 = (float*)wsc;
    __hip_bfloat16* s1 = (__hip_bfloat16*)(wsc + SZA);
    __hip_bfloat16* s2 = (__hip_bfloat16*)(wsc + SZA);
    __hip_bfloat16* s3 = (__hip_bfloat16*)(wsc + SZA);

    char* csr = wsc + SZA + SZB;
    int*  cnt    = (int*)csr;
    int*  rs     = (int*)(csr + (size_t)N * 4);
    int*  cursor = (int*)(csr + (size_t)N * 8);
    int*  bsum   = (int*)(csr + (size_t)N * 12);
    int*  bofs   = bsum + 64;
    int2* edges  = (int2*)(bofs + 64);

    const int B = 256;
    auto cdiv = [](long a, long b) { return (int)((a + b - 1) / b); };
    const int nb = cdiv(N, SCAN_CHUNK);

    // ---- CSR build (shared by all 3 layers) ----
    hipMemsetAsync(cnt, 0, (size_t)N * sizeof(int), stream);
    hist_kernel<<<cdiv(E, B), B, 0, stream>>>(erow, cnt, E);
    scan1_kernel<<<nb, SCAN_T, 0, stream>>>(cnt, rs, bsum, N);
    scan2_kernel<<<1, 64, 0, stream>>>(bsum, bofs, nb);
    scan3_kernel<<<cdiv(N, B), B, 0, stream>>>(cnt, rs, cursor, bofs, N);
    scatter_edges_kernel<<<cdiv(E, B), B, 0, stream>>>(erow, ecol, ew, cursor, edges, E);

    // ---- Layer 1: 64 -> 64 ----
    gemm_kernel<64, 64, false><<<cdiv((long)N * 16, B), B, 0, stream>>>(x, W1, s1, N);
    agg_kernel<64, false><<<cdiv((long)N * 64, B), B, 0, stream>>>(rs, edges, s1, b1, a1, N, E);

    // ---- Layer 2: 64 -> 32 ----  (s2 overwrites s1; a1 still live as input)
    gemm_kernel<64, 32, true><<<cdiv((long)N * 8, B), B, 0, stream>>>(a1, W2, s2, N);
    agg_kernel<32, false><<<cdiv((long)N * 32, B), B, 0, stream>>>(rs, edges, s2, b2, a2, N, E);

    // ---- Layer 3: 32 -> 16 ---- (s3 overwrites s2; a2 read from region A)
    gemm_kernel<32, 16, true><<<cdiv((long)N * 4, B), B, 0, stream>>>(a2, W3, s3, N);
    agg_kernel<16, true><<<cdiv((long)N * 16, B), B, 0, stream>>>(rs, edges, s3, b3, out, N, E);
}